// Round 3
// baseline (1173.292 us; speedup 1.0000x reference)
//
#include <hip/hip_runtime.h>
#include <hip/hip_bf16.h>
#include <stdint.h>

#define B_   8
#define V_   49152
#define FIN  64
#define KCH  3
#define FOUT 64

typedef unsigned short ushort_t;

__device__ __forceinline__ float bf2f(ushort_t h) {
    union { unsigned int u; float f; } x; x.u = ((unsigned int)h) << 16; return x.f;
}
__device__ __forceinline__ ushort_t f2bf(float f) {
    union { unsigned int u; float f; } x; x.f = f;
    unsigned int u = x.u;
    unsigned int r = u + 0x7fffu + ((u >> 16) & 1u);   // round-to-nearest-even
    return (ushort_t)(r >> 16);
}

// flagged scalar load: bf==1 -> data is bf16 (ushort), bf==0 -> data is fp32
__device__ __forceinline__ float loadf(const void* p, size_t i, int bf) {
    if (bf) return bf2f(((const ushort_t*)p)[i]);
    return ((const float*)p)[i];
}

__device__ __forceinline__ void load8_flag(const void* p, size_t off, int bf, float* r) {
    if (bf) {
        union { uint4 q; ushort_t s[8]; } u;
        u.q = *(const uint4*)((const ushort_t*)p + off);
        #pragma unroll
        for (int i = 0; i < 8; i++) r[i] = bf2f(u.s[i]);
    } else {
        const float* f = (const float*)p + off;
        #pragma unroll
        for (int i = 0; i < 8; i++) r[i] = f[i];
    }
}
__device__ __forceinline__ void load8_bf(const ushort_t* p, size_t off, float* r) {
    union { uint4 q; ushort_t s[8]; } u;
    u.q = *(const uint4*)(p + off);
    #pragma unroll
    for (int i = 0; i < 8; i++) r[i] = bf2f(u.s[i]);
}

// Detect whether float arrays are bf16 (1) or fp32 (0).
// bf16: low ushort of each 32b word has a bf16 exponent pattern (~100% of N(0,1) data)
// fp32: low ushort is random mantissa bits (~12% hit the pattern window)
__global__ void detect_kernel(const unsigned int* __restrict__ w, int* __restrict__ flag) {
    __shared__ int c;
    if (threadIdx.x == 0) c = 0;
    __syncthreads();
    int local = 0;
    for (int i = threadIdx.x; i < 1024; i += 64) {
        unsigned int lo = w[i] & 0xFFFFu;
        unsigned int e = (lo >> 7) & 0xFFu;
        if (e >= 110u && e <= 140u) local++;
    }
    atomicAdd(&c, local);
    __syncthreads();
    if (threadIdx.x == 0) *flag = (c >= 512) ? 1 : 0;
}

__global__ void fill_sentinel(ushort_t* out, int n) {
    int i = blockIdx.x * blockDim.x + threadIdx.x;
    if (i < n) out[i] = f2bf(9999.0f);
}

__global__ void zero_kernel(int* p, int n) {
    int i = blockIdx.x * blockDim.x + threadIdx.x;
    if (i < n) p[i] = 0;
}

__global__ void hist_kernel(const int* __restrict__ rows, int nnz, int* __restrict__ counts) {
    int i = blockIdx.x * blockDim.x + threadIdx.x;
    if (i < nnz) atomicAdd(&counts[rows[i]], 1);
}

// simple, obviously-correct single-block exclusive scan: offsets[0..V_]
__global__ __launch_bounds__(1024) void scan_kernel(const int* __restrict__ counts,
                                                    int* __restrict__ offsets) {
    __shared__ int s[1024];
    int t = threadIdx.x;
    const int C = V_ / 1024;   // 48
    int base_i = t * C;
    int sum = 0;
    for (int j = 0; j < C; j++) sum += counts[base_i + j];
    s[t] = sum;
    __syncthreads();
    for (int off = 1; off < 1024; off <<= 1) {       // Hillis-Steele inclusive
        int v = (t >= off) ? s[t - off] : 0;
        __syncthreads();
        s[t] += v;
        __syncthreads();
    }
    int run = (t == 0) ? 0 : s[t - 1];
    for (int j = 0; j < C; j++) {
        offsets[base_i + j] = run;
        run += counts[base_i + j];
    }
    if (t == 1023) offsets[V_] = run;
}

__global__ void bucket_kernel(const int* __restrict__ rows, const int* __restrict__ cols,
                              const void* __restrict__ vals, int nnz,
                              const int* __restrict__ offsets, int* __restrict__ cursor,
                              int* __restrict__ e_col, float* __restrict__ e_val,
                              const int* __restrict__ flag) {
    int i = blockIdx.x * blockDim.x + threadIdx.x;
    if (i >= nnz) return;
    int bf = *flag;
    int r = rows[i];
    int p = offsets[r] + atomicAdd(&cursor[r], 1);
    if (p >= 0 && p < nnz) {
        e_col[p] = cols[i];
        e_val[p] = loadf(vals, (size_t)i, bf);
    }
}

// CSR integrity check -> sets *bad nonzero on any inconsistency
__global__ void validate_kernel(const int* __restrict__ offsets, const int* __restrict__ cursor,
                                const int* __restrict__ counts, const int* __restrict__ e_col,
                                int nnz, int* __restrict__ bad) {
    int i = blockIdx.x * blockDim.x + threadIdx.x;
    if (i < V_) {
        int c = offsets[i + 1] - offsets[i];
        if (c < 0 || c != counts[i] || c != cursor[i]) atomicOr(bad, 1);
    }
    if (i == 0 && offsets[V_] != nnz) atomicOr(bad, 2);
    if (i < nnz) {
        if ((unsigned)e_col[i] >= (unsigned)V_) atomicOr(bad, 4);
    }
}

__global__ void poison_if_bad(const int* __restrict__ bad, const int* __restrict__ flag,
                              ushort_t* __restrict__ out, float* __restrict__ outf, int n) {
    if (*bad == 0) return;
    int i = blockIdx.x * blockDim.x + threadIdx.x;
    if (i >= n) return;
    if (*flag) out[i] = f2bf(1000.0f);
    else       outf[i] = 1000.0f;
}

// x1[v][b][fi] = sum_e val_e * inputs[b][col_e][fi]
__global__ __launch_bounds__(512) void spmm1_kernel(const void* __restrict__ inp,
                                                    const int* __restrict__ offsets,
                                                    const int* __restrict__ e_col,
                                                    const float* __restrict__ e_val,
                                                    ushort_t* __restrict__ x1, int nnz,
                                                    const int* __restrict__ flag) {
    int v = blockIdx.x, tid = threadIdx.x;
    int bf = *flag;
    int b = tid >> 6, fi = tid & 63;
    __shared__ int   s_col[512];
    __shared__ float s_val[512];
    int beg = offsets[v], end = offsets[v + 1];
    beg = max(0, min(beg, nnz));
    end = max(beg, min(end, nnz));
    float acc = 0.f;
    for (int cbeg = beg; cbeg < end; cbeg += 512) {
        int n = min(512, end - cbeg);
        if (tid < n) { s_col[tid] = e_col[cbeg + tid]; s_val[tid] = e_val[cbeg + tid]; }
        __syncthreads();
        for (int e = 0; e < n; e++) {
            int col = s_col[e];
            if ((unsigned)col < (unsigned)V_)
                acc += s_val[e] * loadf(inp, ((size_t)b * V_ + col) * 64 + fi, bf);
        }
        __syncthreads();
    }
    x1[((size_t)v * 8 + b) * 64 + fi] = f2bf(acc);
}

// x2[v][b][fi] = 2 * sum_e val_e * x1[col_e][b][fi] - inputs[b][v][fi]
__global__ __launch_bounds__(512) void spmm2_kernel(const void* __restrict__ inp,
                                                    const ushort_t* __restrict__ x1,
                                                    const int* __restrict__ offsets,
                                                    const int* __restrict__ e_col,
                                                    const float* __restrict__ e_val,
                                                    ushort_t* __restrict__ x2, int nnz,
                                                    const int* __restrict__ flag) {
    int v = blockIdx.x, tid = threadIdx.x;
    int bf = *flag;
    int b = tid >> 6, fi = tid & 63;
    __shared__ int   s_col[512];
    __shared__ float s_val[512];
    int beg = offsets[v], end = offsets[v + 1];
    beg = max(0, min(beg, nnz));
    end = max(beg, min(end, nnz));
    float acc = 0.f;
    for (int cbeg = beg; cbeg < end; cbeg += 512) {
        int n = min(512, end - cbeg);
        if (tid < n) { s_col[tid] = e_col[cbeg + tid]; s_val[tid] = e_val[cbeg + tid]; }
        __syncthreads();
        for (int e = 0; e < n; e++) {
            int col = s_col[e];
            if ((unsigned)col < (unsigned)V_)
                acc += s_val[e] * bf2f(x1[((size_t)col * 8 + b) * 64 + fi]);
        }
        __syncthreads();
    }
    float res = 2.f * acc - loadf(inp, ((size_t)b * V_ + v) * 64 + fi, bf);
    x2[((size_t)v * 8 + b) * 64 + fi] = f2bf(res);
}

// out[b][v][fo] = bias[fo] + sum_fi x0*W[fi][0][fo] + x1*W[fi][1][fo] + x2*W[fi][2][fo]
__global__ __launch_bounds__(256) void gemm_kernel(const void* __restrict__ inp,
                                                   const ushort_t* __restrict__ x1,
                                                   const ushort_t* __restrict__ x2,
                                                   const void* __restrict__ wgt,
                                                   const void* __restrict__ bias,
                                                   ushort_t* __restrict__ out,
                                                   float* __restrict__ outf,
                                                   const int* __restrict__ flag) {
    __shared__ float wl[192 * 64];   // [fi*3+k][fo] as fp32, 48 KB
    __shared__ float bl[64];
    int tid = threadIdx.x;
    int bf = *flag;
    for (int idx = tid; idx < 192 * 64; idx += 256) wl[idx] = loadf(wgt, idx, bf);
    if (tid < 64) bl[tid] = loadf(bias, tid, bf);
    __syncthreads();

    int lane = tid & 63, wv = tid >> 6;
    int m0 = blockIdx.x * 16 + wv * 4;           // 4 consecutive rows m = b*V + v
    int b  = m0 / V_;                            // block never straddles a b boundary
    int v0 = m0 - b * V_;

    const size_t ibase = ((size_t)b * V_ + v0) * 64;   // inputs/out row base
    const size_t xbase = ((size_t)v0 * 8 + b) * 64;    // x1/x2 row base

    float acc[4];
    #pragma unroll
    for (int j = 0; j < 4; j++) acc[j] = bl[lane];

    for (int f8 = 0; f8 < 8; ++f8) {
        float a0[4][8], a1[4][8], a2[4][8];
        #pragma unroll
        for (int j = 0; j < 4; j++) {
            load8_flag(inp, ibase + (size_t)j * 64  + f8 * 8, bf, a0[j]);
            load8_bf  (x1,  xbase + (size_t)j * 512 + f8 * 8,     a1[j]);
            load8_bf  (x2,  xbase + (size_t)j * 512 + f8 * 8,     a2[j]);
        }
        #pragma unroll
        for (int t = 0; t < 8; t++) {
            int fi = f8 * 8 + t;
            float w0 = wl[(fi * 3 + 0) * 64 + lane];
            float w1 = wl[(fi * 3 + 1) * 64 + lane];
            float w2 = wl[(fi * 3 + 2) * 64 + lane];
            #pragma unroll
            for (int j = 0; j < 4; j++) {
                acc[j] += a0[j][t] * w0 + a1[j][t] * w1 + a2[j][t] * w2;
            }
        }
    }
    if (bf) {
        #pragma unroll
        for (int j = 0; j < 4; j++)
            out[ibase + (size_t)j * 64 + lane] = f2bf(acc[j]);
    } else {
        #pragma unroll
        for (int j = 0; j < 4; j++)
            outf[ibase + (size_t)j * 64 + lane] = acc[j];
    }
}

extern "C" void kernel_launch(void* const* d_in, const int* in_sizes, int n_in,
                              void* d_out, int out_size, void* d_ws, size_t ws_size,
                              hipStream_t stream) {
    const void* inp  = d_in[0];
    const void* wgt  = d_in[1];
    const void* bias = d_in[2];
    const int*  rows = (const int*)d_in[3];
    const int*  cols = (const int*)d_in[4];
    const void* vals = d_in[5];
    int nnz = in_sizes[3];
    ushort_t* out  = (ushort_t*)d_out;
    float*    outf = (float*)d_out;
    (void)n_in;

    char* ws = (char*)d_ws;
    size_t o = 0;
    auto alloc = [&](size_t bytes) { void* p = ws + o; o += (bytes + 255) & ~(size_t)255; return p; };
    int*      flag    = (int*)alloc(4);
    int*      bad     = (int*)alloc(4);
    int*      counts  = (int*)alloc((size_t)V_ * 4);
    int*      offsets = (int*)alloc(((size_t)V_ + 1) * 4);
    int*      cursor  = (int*)alloc((size_t)V_ * 4);
    int*      e_col   = (int*)alloc((size_t)nnz * 4);
    float*    e_val   = (float*)alloc((size_t)nnz * 4);
    ushort_t* x1      = (ushort_t*)alloc((size_t)V_ * 512 * 2);
    ushort_t* x2      = (ushort_t*)alloc((size_t)V_ * 512 * 2);

    if (ws_size < o) {
        // diagnostic: workspace too small -> absmax will be ~9993/~10000
        int n = B_ * V_ * FOUT;
        fill_sentinel<<<(n + 255) / 256, 256, 0, stream>>>(out, n);
        return;
    }

    detect_kernel<<<1, 64, 0, stream>>>((const unsigned int*)inp, flag);
    zero_kernel<<<(V_ + 255) / 256, 256, 0, stream>>>(counts, V_);
    zero_kernel<<<(V_ + 255) / 256, 256, 0, stream>>>(cursor, V_);
    zero_kernel<<<1, 64, 0, stream>>>(bad, 1);
    hist_kernel<<<(nnz + 255) / 256, 256, 0, stream>>>(rows, nnz, counts);
    scan_kernel<<<1, 1024, 0, stream>>>(counts, offsets);
    bucket_kernel<<<(nnz + 255) / 256, 256, 0, stream>>>(rows, cols, vals, nnz,
                                                         offsets, cursor, e_col, e_val, flag);
    validate_kernel<<<(nnz + 255) / 256, 256, 0, stream>>>(offsets, cursor, counts, e_col, nnz, bad);
    spmm1_kernel<<<V_, 512, 0, stream>>>(inp, offsets, e_col, e_val, x1, nnz, flag);
    spmm2_kernel<<<V_, 512, 0, stream>>>(inp, x1, offsets, e_col, e_val, x2, nnz, flag);
    gemm_kernel<<<(B_ * V_) / 16, 256, 0, stream>>>(inp, x1, x2, wgt, bias, out, outf, flag);
    poison_if_bad<<<(B_ * V_ * FOUT + 255) / 256, 256, 0, stream>>>(bad, flag, out, outf, B_ * V_ * FOUT);
}

// Round 4
// 428.861 us; speedup vs baseline: 2.7358x; 2.7358x over previous
//
#include <hip/hip_runtime.h>
#include <hip/hip_bf16.h>
#include <stdint.h>

#define B_   8
#define V_   49152
#define M_   (B_ * V_)        // 393216 GEMM rows
#define GEMM_BLOCKS 1536

typedef unsigned short ushort_t;
typedef __attribute__((ext_vector_type(8))) short short8;
typedef __attribute__((ext_vector_type(4))) float float4v;

__device__ __forceinline__ float bf2f_lo(unsigned int pk) {
    union { unsigned int u; float f; } x; x.u = pk << 16; return x.f;
}
__device__ __forceinline__ float bf2f_hi(unsigned int pk) {
    union { unsigned int u; float f; } x; x.u = pk & 0xffff0000u; return x.f;
}
__device__ __forceinline__ ushort_t f2bf(float f) {
    union { unsigned int u; float f; } x; x.f = f;
    unsigned int u = x.u;
    unsigned int r = u + 0x7fffu + ((u >> 16) & 1u);   // RNE
    return (ushort_t)(r >> 16);
}
__device__ __forceinline__ unsigned int pack2(float a, float b) {
    return ((unsigned int)f2bf(b) << 16) | (unsigned int)f2bf(a);
}

__global__ void fill_sentinel(float* out, int n) {
    int i = blockIdx.x * blockDim.x + threadIdx.x;
    if (i < n) out[i] = 9999.0f;
}

__global__ void zero_kernel(int* p, int n) {
    int i = blockIdx.x * blockDim.x + threadIdx.x;
    if (i < n) p[i] = 0;
}

__global__ void hist_kernel(const int* __restrict__ rows, int nnz, int* __restrict__ counts) {
    int i = blockIdx.x * blockDim.x + threadIdx.x;
    if (i < nnz) atomicAdd(&counts[rows[i]], 1);
}

// single-block exclusive scan: offsets[0..V_]
__global__ __launch_bounds__(1024) void scan_kernel(const int* __restrict__ counts,
                                                    int* __restrict__ offsets) {
    __shared__ int s[1024];
    int t = threadIdx.x;
    const int C = V_ / 1024;   // 48
    int base_i = t * C;
    int sum = 0;
    for (int j = 0; j < C; j++) sum += counts[base_i + j];
    s[t] = sum;
    __syncthreads();
    for (int off = 1; off < 1024; off <<= 1) {
        int v = (t >= off) ? s[t - off] : 0;
        __syncthreads();
        s[t] += v;
        __syncthreads();
    }
    int run = (t == 0) ? 0 : s[t - 1];
    for (int j = 0; j < C; j++) {
        offsets[base_i + j] = run;
        run += counts[base_i + j];
    }
    if (t == 1023) offsets[V_] = run;
}

__global__ void bucket_kernel(const int* __restrict__ rows, const int* __restrict__ cols,
                              const float* __restrict__ vals, int nnz,
                              const int* __restrict__ offsets, int* __restrict__ cursor,
                              int* __restrict__ e_col, float* __restrict__ e_val) {
    int i = blockIdx.x * blockDim.x + threadIdx.x;
    if (i >= nnz) return;
    int r = rows[i];
    int p = offsets[r] + atomicAdd(&cursor[r], 1);
    e_col[p] = cols[i];
    e_val[p] = vals[i];
}

// x0t[(v*8+b)*64 + fi] = bf16(inp[(b*V+v)*64 + fi])
__global__ __launch_bounds__(256) void prep_x0t(const float* __restrict__ inp,
                                                ushort_t* __restrict__ x0t) {
    int idx = blockIdx.x * 256 + threadIdx.x;   // 0 .. V_*32-1
    int f2 = idx & 31, v = idx >> 5;
    #pragma unroll
    for (int b = 0; b < 8; b++) {
        const float* src = inp + ((size_t)b * V_ + v) * 64 + f2 * 2;
        float2 d = *(const float2*)src;
        *(unsigned int*)(x0t + ((size_t)v * 8 + b) * 64 + f2 * 2) = pack2(d.x, d.y);
    }
}

// MFMA B-fragment layout:
// wBf[((kb*4+nt)*64 + lane)*8 + j] = bf16( B[k][n] ),
//   k = kb*32 + (lane>>4)*8 + j  (0..191, = kcheb*64 + fi), n = nt*16 + (lane&15)
//   B[k][n] = wgt[(fi*3+kcheb)*64 + n]
__global__ void prep_w(const float* __restrict__ wgt, ushort_t* __restrict__ wBf) {
    int idx = blockIdx.x * 256 + threadIdx.x;   // 6*4*64*8 = 12288
    if (idx >= 6 * 4 * 64 * 8) return;
    int j = idx & 7, lane = (idx >> 3) & 63, nt = (idx >> 9) & 3, kb = idx >> 11;
    int k = kb * 32 + (lane >> 4) * 8 + j;
    int kc = k >> 6, fi = k & 63;
    int fo = nt * 16 + (lane & 15);
    wBf[idx] = f2bf(wgt[(fi * 3 + kc) * 64 + fo]);
}

// x1[(v*8+b)*64+fi] = sum_e val_e * x0t[(col_e*8+b)*64+fi]
__global__ __launch_bounds__(256) void spmm1_kernel(const ushort_t* __restrict__ x0t,
                                                    const int* __restrict__ offsets,
                                                    const int* __restrict__ e_col,
                                                    const float* __restrict__ e_val,
                                                    ushort_t* __restrict__ x1) {
    int v = blockIdx.x, tid = threadIdx.x;
    int b = tid >> 5, f2 = tid & 31;
    int base = b * 64 + f2 * 2;
    __shared__ int   s_col[64];
    __shared__ float s_val[64];
    int beg = offsets[v], end = offsets[v + 1];
    float ax = 0.f, ay = 0.f;
    for (int c = beg; c < end; c += 64) {
        int n = min(64, end - c);
        if (tid < n) { s_col[tid] = e_col[c + tid]; s_val[tid] = e_val[c + tid]; }
        __syncthreads();
        for (int e = 0; e < n; e++) {
            unsigned int pk = *(const unsigned int*)(x0t + ((size_t)s_col[e] << 9) + base);
            float w = s_val[e];
            ax += w * bf2f_lo(pk);
            ay += w * bf2f_hi(pk);
        }
        __syncthreads();
    }
    *(unsigned int*)(x1 + ((size_t)v << 9) + base) = pack2(ax, ay);
}

// x2[(v*8+b)*64+fi] = 2*sum_e val_e * x1[(col_e*8+b)*64+fi] - x0t[(v*8+b)*64+fi]
__global__ __launch_bounds__(256) void spmm2_kernel(const ushort_t* __restrict__ x0t,
                                                    const ushort_t* __restrict__ x1,
                                                    const int* __restrict__ offsets,
                                                    const int* __restrict__ e_col,
                                                    const float* __restrict__ e_val,
                                                    ushort_t* __restrict__ x2) {
    int v = blockIdx.x, tid = threadIdx.x;
    int b = tid >> 5, f2 = tid & 31;
    int base = b * 64 + f2 * 2;
    __shared__ int   s_col[64];
    __shared__ float s_val[64];
    int beg = offsets[v], end = offsets[v + 1];
    float ax = 0.f, ay = 0.f;
    for (int c = beg; c < end; c += 64) {
        int n = min(64, end - c);
        if (tid < n) { s_col[tid] = e_col[c + tid]; s_val[tid] = e_val[c + tid]; }
        __syncthreads();
        for (int e = 0; e < n; e++) {
            unsigned int pk = *(const unsigned int*)(x1 + ((size_t)s_col[e] << 9) + base);
            float w = s_val[e];
            ax += w * bf2f_lo(pk);
            ay += w * bf2f_hi(pk);
        }
        __syncthreads();
    }
    unsigned int p0 = *(const unsigned int*)(x0t + ((size_t)v << 9) + base);
    float rx = 2.f * ax - bf2f_lo(p0);
    float ry = 2.f * ay - bf2f_hi(p0);
    *(unsigned int*)(x2 + ((size_t)v << 9) + base) = pack2(rx, ry);
}

// out[(b*V+v)*64+fo] = bias[fo] + sum_k A[m][k]*B[k][fo],  m=v*8+b, A=[x0t|x1|x2]
__global__ __launch_bounds__(256) void gemm_kernel(const ushort_t* __restrict__ x0t,
                                                   const ushort_t* __restrict__ x1,
                                                   const ushort_t* __restrict__ x2,
                                                   const ushort_t* __restrict__ wBf,
                                                   const float* __restrict__ bias,
                                                   float* __restrict__ out) {
    int tid = threadIdx.x, lane = tid & 63, wv = tid >> 6;
    int quad = lane >> 4, col = lane & 15;

    // preload B fragments: 24 x short8 = 96 VGPRs
    short8 Bf[6][4];
    #pragma unroll
    for (int kb = 0; kb < 6; kb++)
        #pragma unroll
        for (int nt = 0; nt < 4; nt++)
            Bf[kb][nt] = *(const short8*)(wBf + ((size_t)((kb * 4 + nt) * 64 + lane)) * 8);

    float bv[4];
    #pragma unroll
    for (int nt = 0; nt < 4; nt++) bv[nt] = bias[nt * 16 + col];

    const int stride = GEMM_BLOCKS * 64;
    for (int m0 = (blockIdx.x * 4 + wv) * 16; m0 < M_; m0 += stride) {
        float4v acc[4];
        #pragma unroll
        for (int nt = 0; nt < 4; nt++) acc[nt] = (float4v){0.f, 0.f, 0.f, 0.f};

        const size_t arow = ((size_t)(m0 + col)) * 64 + quad * 8;  // A: row=m0+col(lane&15), k=quad*8+j
        #pragma unroll
        for (int kb = 0; kb < 6; kb++) {
            const ushort_t* src = (kb < 2) ? x0t : (kb < 4) ? x1 : x2;
            short8 A = *(const short8*)(src + arow + (kb & 1) * 32);
            #pragma unroll
            for (int nt = 0; nt < 4; nt++)
                acc[nt] = __builtin_amdgcn_mfma_f32_16x16x32_bf16(A, Bf[kb][nt], acc[nt], 0, 0, 0);
        }
        #pragma unroll
        for (int reg = 0; reg < 4; reg++) {
            int m = m0 + quad * 4 + reg;          // C/D: row = quad*4+reg, col = lane&15
            int v = m >> 3, b = m & 7;
            float* orow = out + ((size_t)b * V_ + v) * 64;
            #pragma unroll
            for (int nt = 0; nt < 4; nt++)
                orow[nt * 16 + col] = acc[nt][reg] + bv[nt];
        }
    }
}

extern "C" void kernel_launch(void* const* d_in, const int* in_sizes, int n_in,
                              void* d_out, int out_size, void* d_ws, size_t ws_size,
                              hipStream_t stream) {
    const float* inp  = (const float*)d_in[0];
    const float* wgt  = (const float*)d_in[1];
    const float* bias = (const float*)d_in[2];
    const int*   rows = (const int*)d_in[3];
    const int*   cols = (const int*)d_in[4];
    const float* vals = (const float*)d_in[5];
    int nnz = in_sizes[3];
    float* out = (float*)d_out;
    (void)n_in; (void)out_size;

    char* ws = (char*)d_ws;
    size_t o = 0;
    auto alloc = [&](size_t bytes) { void* p = ws + o; o += (bytes + 255) & ~(size_t)255; return p; };
    int*      counts  = (int*)alloc((size_t)V_ * 4);
    int*      cursor  = (int*)alloc((size_t)V_ * 4);
    int*      offsets = (int*)alloc(((size_t)V_ + 1) * 4);
    int*      e_col   = (int*)alloc((size_t)nnz * 4);
    float*    e_val   = (float*)alloc((size_t)nnz * 4);
    ushort_t* x0t     = (ushort_t*)alloc((size_t)M_ * 64 * 2);
    ushort_t* x1      = (ushort_t*)alloc((size_t)M_ * 64 * 2);
    ushort_t* x2      = (ushort_t*)alloc((size_t)M_ * 64 * 2);
    ushort_t* wBf     = (ushort_t*)alloc(6 * 4 * 64 * 8 * 2);

    if (ws_size < o) {
        fill_sentinel<<<(M_ * 64 + 255) / 256, 256, 0, stream>>>(out, M_ * 64);
        return;
    }

    zero_kernel<<<(2 * V_ + 255) / 256, 256, 0, stream>>>(counts, 2 * V_);  // counts+cursor adjacent
    hist_kernel<<<(nnz + 255) / 256, 256, 0, stream>>>(rows, nnz, counts);
    scan_kernel<<<1, 1024, 0, stream>>>(counts, offsets);
    bucket_kernel<<<(nnz + 255) / 256, 256, 0, stream>>>(rows, cols, vals, nnz,
                                                         offsets, cursor, e_col, e_val);
    prep_x0t<<<(V_ * 32) / 256, 256, 0, stream>>>(inp, x0t);
    prep_w<<<48, 256, 0, stream>>>(wgt, wBf);
    spmm1_kernel<<<V_, 256, 0, stream>>>(x0t, offsets, e_col, e_val, x1);
    spmm2_kernel<<<V_, 256, 0, stream>>>(x0t, x1, offsets, e_col, e_val, x2);
    gemm_kernel<<<GEMM_BLOCKS, 256, 0, stream>>>(x0t, x1, x2, wBf, bias, out);
}

// Round 5
// 391.930 us; speedup vs baseline: 2.9936x; 1.0942x over previous
//
#include <hip/hip_runtime.h>
#include <stdint.h>

#define B_   8
#define V_   49152
#define M_   (B_ * V_)        // 393216 GEMM rows

typedef unsigned short ushort_t;
typedef __attribute__((ext_vector_type(8))) short short8;
typedef __attribute__((ext_vector_type(4))) float float4v;

__device__ __forceinline__ float bf2f_lo(unsigned int pk) {
    union { unsigned int u; float f; } x; x.u = pk << 16; return x.f;
}
__device__ __forceinline__ float bf2f_hi(unsigned int pk) {
    union { unsigned int u; float f; } x; x.u = pk & 0xffff0000u; return x.f;
}
__device__ __forceinline__ ushort_t f2bf(float f) {
    union { unsigned int u; float f; } x; x.f = f;
    unsigned int u = x.u;
    unsigned int r = u + 0x7fffu + ((u >> 16) & 1u);   // RNE
    return (ushort_t)(r >> 16);
}
__device__ __forceinline__ unsigned int pack2(float a, float b) {
    return ((unsigned int)f2bf(b) << 16) | (unsigned int)f2bf(a);
}
// acc[0..7] += w * (8 bf16 in p)
__device__ __forceinline__ void fma8(float* acc, float w, const uint4& p) {
    const unsigned int* u = (const unsigned int*)&p;
    #pragma unroll
    for (int i = 0; i < 4; i++) {
        acc[2 * i]     += w * bf2f_lo(u[i]);
        acc[2 * i + 1] += w * bf2f_hi(u[i]);
    }
}

__global__ void fill_sentinel(float* out, int n) {
    int i = blockIdx.x * blockDim.x + threadIdx.x;
    if (i < n) out[i] = 9999.0f;
}

__global__ void zero_kernel(int* p, int n) {
    int i = blockIdx.x * blockDim.x + threadIdx.x;
    if (i < n) p[i] = 0;
}

__global__ void hist_kernel(const int* __restrict__ rows, int nnz, int* __restrict__ counts) {
    int i = blockIdx.x * blockDim.x + threadIdx.x;
    if (i < nnz) atomicAdd(&counts[rows[i]], 1);
}

// single-block exclusive scan: offsets[0..V_]
__global__ __launch_bounds__(1024) void scan_kernel(const int* __restrict__ counts,
                                                    int* __restrict__ offsets) {
    __shared__ int s[1024];
    int t = threadIdx.x;
    const int C = V_ / 1024;   // 48
    int base_i = t * C;
    int sum = 0;
    for (int j = 0; j < C; j++) sum += counts[base_i + j];
    s[t] = sum;
    __syncthreads();
    for (int off = 1; off < 1024; off <<= 1) {
        int v = (t >= off) ? s[t - off] : 0;
        __syncthreads();
        s[t] += v;
        __syncthreads();
    }
    int run = (t == 0) ? 0 : s[t - 1];
    for (int j = 0; j < C; j++) {
        offsets[base_i + j] = run;
        run += counts[base_i + j];
    }
    if (t == 1023) offsets[V_] = run;
}

__global__ void bucket_kernel(const int* __restrict__ rows, const int* __restrict__ cols,
                              const float* __restrict__ vals, int nnz,
                              const int* __restrict__ offsets, int* __restrict__ cursor,
                              int* __restrict__ e_col, float* __restrict__ e_val) {
    int i = blockIdx.x * blockDim.x + threadIdx.x;
    if (i >= nnz) return;
    int r = rows[i];
    int p = offsets[r] + atomicAdd(&cursor[r], 1);
    e_col[p] = cols[i];
    e_val[p] = vals[i];
}

// x0t[(v*8+b)*64 + fi] = bf16(inp[(b*V+v)*64 + fi])
__global__ __launch_bounds__(256) void prep_x0t(const float* __restrict__ inp,
                                                ushort_t* __restrict__ x0t) {
    int idx = blockIdx.x * 256 + threadIdx.x;   // 0 .. V_*32-1
    int f2 = idx & 31, v = idx >> 5;
    #pragma unroll
    for (int b = 0; b < 8; b++) {
        const float* src = inp + ((size_t)b * V_ + v) * 64 + f2 * 2;
        float2 d = *(const float2*)src;
        *(unsigned int*)(x0t + ((size_t)v * 8 + b) * 64 + f2 * 2) = pack2(d.x, d.y);
    }
}

// MFMA B-fragment layout (verified round 4):
// wBf[((kb*4+nt)*64 + lane)*8 + j] = bf16(B[k][n]), k=kb*32+(lane>>4)*8+j, n=nt*16+(lane&15)
// B[k][n] = wgt[(fi*3+kc)*64 + n], kc=k>>6, fi=k&63
__global__ void prep_w(const float* __restrict__ wgt, ushort_t* __restrict__ wBf) {
    int idx = blockIdx.x * 256 + threadIdx.x;   // 12288
    if (idx >= 6 * 4 * 64 * 8) return;
    int j = idx & 7, lane = (idx >> 3) & 63, nt = (idx >> 9) & 3, kb = idx >> 11;
    int k = kb * 32 + (lane >> 4) * 8 + j;
    int kc = k >> 6, fi = k & 63;
    int fo = nt * 16 + (lane & 15);
    wBf[idx] = f2bf(wgt[(fi * 3 + kc) * 64 + fo]);
}

// gather body: acc[16] += sum over edges of v of val * src[(col*8+b)*64 + f8*16 .. +16]
__device__ __forceinline__ void gather16(const ushort_t* __restrict__ src,
                                         const int* __restrict__ e_col,
                                         const float* __restrict__ e_val,
                                         int beg, int end, int b, int f8, float* acc) {
    int e = beg;
    for (; e + 4 <= end; e += 4) {
        int c0 = e_col[e], c1 = e_col[e + 1], c2 = e_col[e + 2], c3 = e_col[e + 3];
        float w0 = e_val[e], w1 = e_val[e + 1], w2 = e_val[e + 2], w3 = e_val[e + 3];
        const ushort_t* p0 = src + ((size_t)c0 * 512) + b * 64 + f8 * 16;
        const ushort_t* p1 = src + ((size_t)c1 * 512) + b * 64 + f8 * 16;
        const ushort_t* p2 = src + ((size_t)c2 * 512) + b * 64 + f8 * 16;
        const ushort_t* p3 = src + ((size_t)c3 * 512) + b * 64 + f8 * 16;
        uint4 a0 = *(const uint4*)p0, b0 = *(const uint4*)(p0 + 8);
        uint4 a1 = *(const uint4*)p1, b1 = *(const uint4*)(p1 + 8);
        uint4 a2 = *(const uint4*)p2, b2 = *(const uint4*)(p2 + 8);
        uint4 a3 = *(const uint4*)p3, b3 = *(const uint4*)(p3 + 8);
        fma8(acc, w0, a0); fma8(acc + 8, w0, b0);
        fma8(acc, w1, a1); fma8(acc + 8, w1, b1);
        fma8(acc, w2, a2); fma8(acc + 8, w2, b2);
        fma8(acc, w3, a3); fma8(acc + 8, w3, b3);
    }
    for (; e < end; e++) {
        int c = e_col[e];
        float w = e_val[e];
        const ushort_t* p = src + ((size_t)c * 512) + b * 64 + f8 * 16;
        uint4 a = *(const uint4*)p, bq = *(const uint4*)(p + 8);
        fma8(acc, w, a); fma8(acc + 8, w, bq);
    }
}

// x1[(v*8+b)*64+fi] = sum_e val_e * x0t[(col_e*8+b)*64+fi]; block = 8 vertices
__global__ __launch_bounds__(256) void spmm1_kernel(const ushort_t* __restrict__ x0t,
                                                    const int* __restrict__ offsets,
                                                    const int* __restrict__ e_col,
                                                    const float* __restrict__ e_val,
                                                    ushort_t* __restrict__ x1) {
    int t = threadIdx.x;
    int vi = t >> 5, b = (t >> 2) & 7, f8 = t & 3;
    int v = blockIdx.x * 8 + vi;
    float acc[16];
    #pragma unroll
    for (int i = 0; i < 16; i++) acc[i] = 0.f;
    gather16(x0t, e_col, e_val, offsets[v], offsets[v + 1], b, f8, acc);
    unsigned int opk[8];
    #pragma unroll
    for (int i = 0; i < 8; i++) opk[i] = pack2(acc[2 * i], acc[2 * i + 1]);
    ushort_t* dst = x1 + ((size_t)v * 8 + b) * 64 + f8 * 16;
    *(uint4*)dst       = make_uint4(opk[0], opk[1], opk[2], opk[3]);
    *(uint4*)(dst + 8) = make_uint4(opk[4], opk[5], opk[6], opk[7]);
}

// Fused: x2 (into LDS) + GEMM over 64 rows (8 v) per block + bias + out write.
__global__ __launch_bounds__(256) void spmm2_gemm(const ushort_t* __restrict__ x0t,
                                                  const ushort_t* __restrict__ x1,
                                                  const int* __restrict__ offsets,
                                                  const int* __restrict__ e_col,
                                                  const float* __restrict__ e_val,
                                                  const ushort_t* __restrict__ wBf,
                                                  const float* __restrict__ bias,
                                                  float* __restrict__ out) {
    __shared__ ushort_t sh[64 * 72];        // x2 rows, padded stride 72 shorts (144 B)
    int t = threadIdx.x;
    int vi = t >> 5, b = (t >> 2) & 7, f8 = t & 3;
    int v0 = blockIdx.x * 8;
    int v = v0 + vi;
    float acc[16];
    #pragma unroll
    for (int i = 0; i < 16; i++) acc[i] = 0.f;
    gather16(x1, e_col, e_val, offsets[v], offsets[v + 1], b, f8, acc);

    // x2 = 2*acc - x0
    size_t r = (size_t)v * 8 + b;
    const ushort_t* x0p = x0t + r * 64 + f8 * 16;
    uint4 qa = *(const uint4*)x0p, qb = *(const uint4*)(x0p + 8);
    const unsigned int* ua = (const unsigned int*)&qa;
    const unsigned int* ub = (const unsigned int*)&qb;
    unsigned int opk[8];
    #pragma unroll
    for (int i = 0; i < 4; i++)
        opk[i] = pack2(2.f * acc[2 * i] - bf2f_lo(ua[i]),
                       2.f * acc[2 * i + 1] - bf2f_hi(ua[i]));
    #pragma unroll
    for (int i = 0; i < 4; i++)
        opk[4 + i] = pack2(2.f * acc[8 + 2 * i] - bf2f_lo(ub[i]),
                           2.f * acc[8 + 2 * i + 1] - bf2f_hi(ub[i]));
    int mg = vi * 8 + b;
    ushort_t* dst = sh + mg * 72 + f8 * 16;
    *(uint4*)dst       = make_uint4(opk[0], opk[1], opk[2], opk[3]);
    *(uint4*)(dst + 8) = make_uint4(opk[4], opk[5], opk[6], opk[7]);
    __syncthreads();

    // ---- GEMM phase: wave wv handles rows [wv*16, wv*16+16) of this 64-row tile
    int lane = t & 63, wv = t >> 6;
    int quad = lane >> 4, col = lane & 15;

    short8 Bf[6][4];
    #pragma unroll
    for (int kb = 0; kb < 6; kb++)
        #pragma unroll
        for (int nt = 0; nt < 4; nt++)
            Bf[kb][nt] = *(const short8*)(wBf + ((size_t)((kb * 4 + nt) * 64 + lane)) * 8);

    float bv[4];
    #pragma unroll
    for (int nt = 0; nt < 4; nt++) bv[nt] = bias[nt * 16 + col];

    float4v accm[4];
    #pragma unroll
    for (int nt = 0; nt < 4; nt++) accm[nt] = (float4v){0.f, 0.f, 0.f, 0.f};

    int m0 = v0 * 8 + wv * 16;
    size_t arow = (size_t)(m0 + col) * 64 + quad * 8;   // A: row=lane&15, k=quad*8+j
    #pragma unroll
    for (int p = 0; p < 2; p++) {
        short8 A = *(const short8*)(x0t + arow + p * 32);
        #pragma unroll
        for (int nt = 0; nt < 4; nt++)
            accm[nt] = __builtin_amdgcn_mfma_f32_16x16x32_bf16(A, Bf[p][nt], accm[nt], 0, 0, 0);
    }
    #pragma unroll
    for (int p = 0; p < 2; p++) {
        short8 A = *(const short8*)(x1 + arow + p * 32);
        #pragma unroll
        for (int nt = 0; nt < 4; nt++)
            accm[nt] = __builtin_amdgcn_mfma_f32_16x16x32_bf16(A, Bf[2 + p][nt], accm[nt], 0, 0, 0);
    }
    #pragma unroll
    for (int p = 0; p < 2; p++) {
        short8 A = *(const short8*)(sh + (wv * 16 + col) * 72 + quad * 8 + p * 32);
        #pragma unroll
        for (int nt = 0; nt < 4; nt++)
            accm[nt] = __builtin_amdgcn_mfma_f32_16x16x32_bf16(A, Bf[4 + p][nt], accm[nt], 0, 0, 0);
    }

    #pragma unroll
    for (int reg = 0; reg < 4; reg++) {
        int m = m0 + quad * 4 + reg;        // C/D: row = quad*4+reg, col = lane&15
        int vv = m >> 3, bb = m & 7;
        float* orow = out + ((size_t)bb * V_ + vv) * 64;
        #pragma unroll
        for (int nt = 0; nt < 4; nt++)
            orow[nt * 16 + col] = accm[nt][reg] + bv[nt];
    }
}

extern "C" void kernel_launch(void* const* d_in, const int* in_sizes, int n_in,
                              void* d_out, int out_size, void* d_ws, size_t ws_size,
                              hipStream_t stream) {
    const float* inp  = (const float*)d_in[0];
    const float* wgt  = (const float*)d_in[1];
    const float* bias = (const float*)d_in[2];
    const int*   rows = (const int*)d_in[3];
    const int*   cols = (const int*)d_in[4];
    const float* vals = (const float*)d_in[5];
    int nnz = in_sizes[3];
    float* out = (float*)d_out;
    (void)n_in; (void)out_size;

    char* ws = (char*)d_ws;
    size_t o = 0;
    auto alloc = [&](size_t bytes) { void* p = ws + o; o += (bytes + 255) & ~(size_t)255; return p; };
    int*      counts  = (int*)alloc((size_t)V_ * 4);
    int*      cursor  = (int*)alloc((size_t)V_ * 4);
    int*      offsets = (int*)alloc(((size_t)V_ + 1) * 4);
    int*      e_col   = (int*)alloc((size_t)nnz * 4);
    float*    e_val   = (float*)alloc((size_t)nnz * 4);
    ushort_t* x0t     = (ushort_t*)alloc((size_t)M_ * 64 * 2);
    ushort_t* x1      = (ushort_t*)alloc((size_t)M_ * 64 * 2);
    ushort_t* wBf     = (ushort_t*)alloc(6 * 4 * 64 * 8 * 2);

    if (ws_size < o) {
        fill_sentinel<<<(M_ * 64 + 255) / 256, 256, 0, stream>>>(out, M_ * 64);
        return;
    }

    zero_kernel<<<(2 * V_ + 255) / 256, 256, 0, stream>>>(counts, 2 * V_);  // counts+cursor adjacent
    hist_kernel<<<(nnz + 255) / 256, 256, 0, stream>>>(rows, nnz, counts);
    scan_kernel<<<1, 1024, 0, stream>>>(counts, offsets);
    bucket_kernel<<<(nnz + 255) / 256, 256, 0, stream>>>(rows, cols, vals, nnz,
                                                         offsets, cursor, e_col, e_val);
    prep_x0t<<<(V_ * 32) / 256, 256, 0, stream>>>(inp, x0t);
    prep_w<<<48, 256, 0, stream>>>(wgt, wBf);
    spmm1_kernel<<<V_ / 8, 256, 0, stream>>>(x0t, offsets, e_col, e_val, x1);
    spmm2_gemm<<<V_ / 8, 256, 0, stream>>>(x0t, x1, offsets, e_col, e_val, wBf, bias, out);
}